// Round 2
// baseline (587.411 us; speedup 1.0000x reference)
//
#include <hip/hip_runtime.h>
#include <cstdint>
#include <cstddef>

#define NTOT 4096
#define DIM  1024
#define NNEG 6
#define KTOP 2048

using u32 = unsigned int;
using u64 = unsigned long long;

typedef __attribute__((ext_vector_type(8))) short bf16x8;
typedef __attribute__((ext_vector_type(4))) float f32x4;

// monotonic float->uint transform (total order, handles negatives)
__device__ __forceinline__ u32 monoU(float f){
  u32 b = __float_as_uint(f);
  return (b & 0x80000000u) ? ~b : (b | 0x80000000u);
}

// fp32 -> bf16 round-to-nearest-even (finite inputs)
__device__ __forceinline__ short f2bf(float f){
  u32 x = __float_as_uint(f);
  u32 r = x + 0x7FFFu + ((x >> 16) & 1u);
  return (short)(r >> 16);
}

// async 16B global->LDS (dest = wave-uniform base + lane*16)
__device__ __forceinline__ void gload16(const short* g, short* l){
  __builtin_amdgcn_global_load_lds(
      (const __attribute__((address_space(1))) void*)(g),
      (__attribute__((address_space(3))) void*)(l), 16, 0, 0);
}

// block-wide sum (blockDim.x == 256), result valid on ALL threads
__device__ __forceinline__ float blockSumAll(float v){
  __shared__ float lds[4];
  for (int o = 32; o; o >>= 1) v += __shfl_down(v, o);
  if ((threadIdx.x & 63) == 0) lds[threadIdx.x >> 6] = v;
  __syncthreads();
  float r = lds[0] + lds[1] + lds[2] + lds[3];
  __syncthreads();
  return r;
}

// ---------------- init ----------------
__global__ void initK(u64* __restrict__ nidxp, u64* __restrict__ best1p,
                      double* __restrict__ lossAcc){
  int i = blockIdx.x * 256 + threadIdx.x;
  if (i < NNEG * NTOT) nidxp[i] = ~0ULL;
  if (i < NTOT) best1p[i] = ~0ULL;
  if (i == 0) *lossAcc = 0.0;
}

// ---------------- per-row normalize stats + bf16 pack ----------------
// norms[row] = t = max(||x||,1e-12); sumn[row] = sum((x/t)^2); packbf = bf16(x/t)
__global__ __launch_bounds__(256) void rowNormPackK(const float* __restrict__ sf,
    float* __restrict__ norms, float* __restrict__ sumn, short* __restrict__ packbf){
  int row = blockIdx.x;                       // 0 .. 8*4096-1
  const float* x = sf + (size_t)row * DIM;
  float4 v = reinterpret_cast<const float4*>(x)[threadIdx.x];
  float s = blockSumAll(v.x*v.x + v.y*v.y + v.z*v.z + v.w*v.w);
  float t = fmaxf(sqrtf(s), 1e-12f);
  float inv = 1.0f / t;
  float a0 = v.x*inv, a1 = v.y*inv, a2 = v.z*inv, a3 = v.w*inv;
  float s2 = blockSumAll(a0*a0 + a1*a1 + a2*a2 + a3*a3);
  short4 pk; pk.x = f2bf(a0); pk.y = f2bf(a1); pk.z = f2bf(a2); pk.w = f2bf(a3);
  reinterpret_cast<short4*>(packbf + (size_t)row * DIM)[threadIdx.x] = pk;
  if (threadIdx.x == 0){ norms[row] = t; sumn[row] = s2; }
}

// ---------------- exact top-k mask (k = N/2) over attention[1] ----------------
__global__ __launch_bounds__(1024) void topkMaskK(const float* __restrict__ att,
                                                  float* __restrict__ mask){
  __shared__ u32 hist[256];
  __shared__ u32 sprefix, sremain;
  __shared__ u32 scan[1024];
  int tid = threadIdx.x;
  u32 u[4];
  #pragma unroll
  for (int e = 0; e < 4; ++e) u[e] = monoU(att[tid*4 + e]);
  if (tid == 0){ sprefix = 0u; sremain = KTOP; }
  __syncthreads();
  for (int shift = 24; shift >= 0; shift -= 8){
    if (tid < 256) hist[tid] = 0u;
    __syncthreads();
    u32 pfx = sprefix;
    #pragma unroll
    for (int e = 0; e < 4; ++e){
      bool cand = (shift == 24) || ((u[e] >> (shift + 8)) == (pfx >> (shift + 8)));
      if (cand) atomicAdd(&hist[(u[e] >> shift) & 255u], 1u);
    }
    __syncthreads();
    if (tid == 0){
      u32 rem = sremain, cum = 0; int b = 255;
      for (; b >= 0; --b){ cum += hist[b]; if (cum >= rem) break; }
      sprefix = pfx | ((u32)b << shift);
      sremain = rem - (cum - hist[b]);
    }
    __syncthreads();
  }
  u32 T = sprefix, need = sremain;
  u32 c = 0;
  #pragma unroll
  for (int e = 0; e < 4; ++e) c += (u[e] == T);
  scan[tid] = c; __syncthreads();
  for (int d = 1; d < 1024; d <<= 1){
    u32 add = (tid >= d) ? scan[tid - d] : 0u;
    __syncthreads();
    scan[tid] += add;
    __syncthreads();
  }
  u32 excl = scan[tid] - c;
  #pragma unroll
  for (int e = 0; e < 4; ++e){
    bool m;
    if (u[e] > T) m = true;
    else if (u[e] == T){ m = (excl < need); excl++; }
    else m = false;
    mask[tid*4 + e] = m ? 1.0f : 0.0f;
  }
}

// ---------------- bf16 MFMA distance kernel (128x128 tile, BK=32) ----------------
// A = frame0 rows (GATHER: gathered via best2 = anchors), B = frame fB rows.
// C[i][j] = dot(An[i], Bn[j]).  Row argmin key = sumn_B[j] - 2*dot (row-const dropped).
// GATHER=false additionally emits per-block column top-2 chunks (for best2/second_min).
template<bool GATHER>
__global__ __launch_bounds__(256) void distMfmaK(
    const short* __restrict__ packbf, const float* __restrict__ sumn,
    const int* __restrict__ best2, u64* __restrict__ rowMinP,
    float* __restrict__ cm1, int* __restrict__ cr1, float* __restrict__ cm2)
{
  __shared__ __align__(16) short As[128*32];
  __shared__ __align__(16) short Bs[128*32];
  const int bi = blockIdx.y, bj = blockIdx.x;
  const int fB = GATHER ? (2 + blockIdx.z) : 1;
  const short* Abf = packbf;                                  // frame 0 (q)
  const short* Bbf = packbf + (size_t)fB * NTOT * DIM;
  const float* sumB = sumn + fB * NTOT;
  u64* rmp = GATHER ? (rowMinP + (size_t)blockIdx.z * NTOT) : rowMinP;

  const int tid  = threadIdx.x;
  const int lane = tid & 63, wv = tid >> 6;
  const int wr = wv >> 1, wc = wv & 1;

  // --- staging: wave wv stages A rows [wv*32,+32) and B rows likewise ---
  // instr s in {0,1}: tile row = wv*32 + s*16 + (lane>>2); linear LDS slot' = lane&3.
  // LDS[row][slot'] must hold k-chunk slot'^f(row), f(row)=(row>>1)&3  (2-way/free banks)
  const int rs0 = wv*32 + (lane>>2);
  const int rs1 = rs0 + 16;
  const int sl  = lane & 3;
  const int ka0 = (sl ^ ((rs0 >> 1) & 3)) << 3;   // element offset within 32-k window
  const int ka1 = (sl ^ ((rs1 >> 1) & 3)) << 3;
  const int ga0 = bi*128 + rs0, ga1 = bi*128 + rs1;
  const int ar0 = GATHER ? best2[ga0] : ga0;
  const int ar1 = GATHER ? best2[ga1] : ga1;
  const short* aS0 = Abf + (size_t)ar0 * DIM + ka0;
  const short* aS1 = Abf + (size_t)ar1 * DIM + ka1;
  const short* bS0 = Bbf + (size_t)(bj*128 + rs0) * DIM + ka0;
  const short* bS1 = Bbf + (size_t)(bj*128 + rs1) * DIM + ka1;
  short* aD0 = As + (wv*32)*32;        // wave-uniform LDS bases
  short* aD1 = As + (wv*32 + 16)*32;
  short* bD0 = Bs + (wv*32)*32;
  short* bD1 = Bs + (wv*32 + 16)*32;

  // --- compute-side fragment addressing (swizzled ds_read_b128) ---
  const int fra  = wr*64 + (lane & 15);           // A tile row base (m adds 16)
  const int frb  = wc*64 + (lane & 15);           // B tile row base (n adds 16)
  const int kblk = lane >> 4;
  // f(row) invariant under +16, so XOR term constant across m/n
  const int aoff = fra*32 + ((kblk ^ ((fra >> 1) & 3)) << 3);
  const int boff = frb*32 + ((kblk ^ ((frb >> 1) & 3)) << 3);

  f32x4 acc[4][4] = {};

  for (int k0 = 0; k0 < DIM; k0 += 32){
    gload16(aS0 + k0, aD0);
    gload16(aS1 + k0, aD1);
    gload16(bS0 + k0, bD0);
    gload16(bS1 + k0, bD1);
    __syncthreads();
    bf16x8 af[4], bfr[4];
    #pragma unroll
    for (int m = 0; m < 4; ++m) af[m]  = *(const bf16x8*)(As + aoff + m*512);
    #pragma unroll
    for (int n = 0; n < 4; ++n) bfr[n] = *(const bf16x8*)(Bs + boff + n*512);
    #pragma unroll
    for (int m = 0; m < 4; ++m)
      #pragma unroll
      for (int n = 0; n < 4; ++n)
        acc[m][n] = __builtin_amdgcn_mfma_f32_16x16x32_bf16(af[m], bfr[n], acc[m][n], 0, 0, 0);
    __syncthreads();
  }

  // --- epilogue 1: fused row-argmin (both modes) ---
  // C frag (m,n) reg r: row = wr*64+m*16+(lane>>4)*4+r, col = wc*64+n*16+(lane&15)
  const int q = lane >> 4;
  float sb[4];
  #pragma unroll
  for (int n = 0; n < 4; ++n) sb[n] = sumB[bj*128 + wc*64 + n*16 + (lane & 15)];
  #pragma unroll
  for (int m = 0; m < 4; ++m){
    #pragma unroll
    for (int r = 0; r < 4; ++r){
      u64 mk = ~0ULL;
      #pragma unroll
      for (int n = 0; n < 4; ++n){
        float key = sb[n] - 2.0f * acc[m][n][r];
        int gj = bj*128 + wc*64 + n*16 + (lane & 15);
        u64 pk = ((u64)monoU(key) << 32) | (u32)gj;
        if (pk < mk) mk = pk;
      }
      #pragma unroll
      for (int off = 1; off <= 8; off <<= 1){
        u64 o = __shfl_xor((unsigned long long)mk, off);
        if (o < mk) mk = o;
      }
      if ((lane & 15) == 0)
        atomicMin(&rmp[bi*128 + wr*64 + m*16 + q*4 + r], mk);
    }
  }

  // --- epilogue 2 (pair only): per-block column top-2 chunk ---
  if constexpr (!GATHER){
    float* Lm1 = reinterpret_cast<float*>(As);          // 128 cols x 8 contribs
    int*   Lr1 = reinterpret_cast<int*>(As) + 1024;
    float* Lm2 = reinterpret_cast<float*>(Bs);
    const float* sumA = sumn;                            // frame 0
    const int gibase = bi*128 + wr*64;
    #pragma unroll
    for (int n = 0; n < 4; ++n){
      float m1 = INFINITY, m2 = INFINITY; int r1 = 0;
      #pragma unroll
      for (int m = 0; m < 4; ++m)
        #pragma unroll
        for (int r = 0; r < 4; ++r){
          int gi = gibase + m*16 + q*4 + r;
          float v = sumA[gi] - 2.0f * acc[m][n][r];     // col-const sumn_B[j] dropped
          if (v < m1){ m2 = m1; m1 = v; r1 = gi; }
          else m2 = fminf(m2, v);
        }
      int c = wc*64 + n*16 + (lane & 15);
      int contrib = wr*4 + q;
      Lm1[c*8 + contrib] = m1;
      Lr1[c*8 + contrib] = r1;
      Lm2[c*8 + contrib] = m2;
    }
    __syncthreads();
    if (tid < 128){
      float M1 = Lm1[tid*8], M2 = Lm2[tid*8]; int R1 = Lr1[tid*8];
      #pragma unroll
      for (int c2 = 1; c2 < 8; ++c2){
        float v1 = Lm1[tid*8 + c2], v2 = Lm2[tid*8 + c2]; int rr = Lr1[tid*8 + c2];
        if (v1 < M1 || (v1 == M1 && rr < R1)){
          M2 = fminf(M2, M1); M1 = v1; R1 = rr; M2 = fminf(M2, v2);
        } else M2 = fminf(M2, v1);
      }
      int gc = bj*128 + tid;
      cm1[(size_t)bi*NTOT + gc] = M1;
      cr1[(size_t)bi*NTOT + gc] = R1;
      cm2[(size_t)bi*NTOT + gc] = M2;
    }
  }
}

// ---------------- column chunk merge + ratio test ----------------
__global__ __launch_bounds__(256) void colMergeK(const float* __restrict__ cm1,
    const int* __restrict__ cr1, const float* __restrict__ cm2,
    const float* __restrict__ sumnP, int* __restrict__ best2, int* __restrict__ ratioOk){
  int j = blockIdx.x * 256 + threadIdx.x;
  float M1 = cm1[j]; int R1 = cr1[j]; float M2 = cm2[j];
  for (int c = 1; c < 32; ++c){
    size_t o = (size_t)c * NTOT + j;
    float v1 = cm1[o]; int rr = cr1[o]; float v2 = cm2[o];
    if (v1 < M1 || (v1 == M1 && rr < R1)){
      M2 = fminf(M2, M1); M1 = v1; R1 = rr; M2 = fminf(M2, v2);
    } else M2 = fminf(M2, v1);
  }
  best2[j] = R1;
  float sbj = sumnP[j];
  float d1 = sqrtf(fmaxf(M1 + sbj, 0.0f));
  float ds = sqrtf(fmaxf(M2 + sbj, 0.0f));
  ratioOk[j] = (d1 / ds <= 0.9f) ? 1 : 0;   // NaN -> false, matches ref
}

// ---------------- valid mask + dpos (exact fp32 recompute) ----------------
__global__ __launch_bounds__(256) void validDposK(const float* __restrict__ sf,
    const float* __restrict__ norms, const u64* __restrict__ best1p,
    const int* __restrict__ best2, const int* __restrict__ ratioOk,
    const float* __restrict__ attm, float* __restrict__ valid, float* __restrict__ dpos){
  int j = blockIdx.x;
  int b2 = best2[j];
  const float* qr = sf + (size_t)b2 * DIM;
  const float* pr = sf + (size_t)(NTOT + j) * DIM;
  float tq = norms[b2], tp = norms[NTOT + j];
  float4 qv = reinterpret_cast<const float4*>(qr)[threadIdx.x];
  float4 pv = reinterpret_cast<const float4*>(pr)[threadIdx.x];
  float d0 = qv.x/tq - pv.x/tp, d1 = qv.y/tq - pv.y/tp;
  float d2 = qv.z/tq - pv.z/tp, d3 = qv.w/tq - pv.w/tp;
  float s = blockSumAll(d0*d0 + d1*d1 + d2*d2 + d3*d3);
  if (threadIdx.x == 0){
    dpos[j] = s;
    int b1 = (int)(best1p[b2] & 0xFFFFFFFFu);
    bool ok = (b1 == j) && (ratioOk[j] != 0) && (attm[j] > 0.0f);
    valid[j] = ok ? 1.0f : 0.0f;
  }
}

// ---------------- dneg + hinge accumulation (exact fp32 recompute) ----------------
__global__ __launch_bounds__(256) void dnegHingeK(const float* __restrict__ sf,
    const float* __restrict__ norms, const int* __restrict__ best2,
    const u64* __restrict__ nidxp, const float* __restrict__ valid,
    const float* __restrict__ dpos, double* __restrict__ lossAcc){
  int j = blockIdx.x, t = blockIdx.y;
  int nidx = (int)(nidxp[(size_t)t * NTOT + j] & 0xFFFFFFFFu);
  int b2 = best2[j];
  const float* ar = sf + (size_t)b2 * DIM;
  const float* nr = sf + (size_t)((2 + t) * NTOT + nidx) * DIM;
  float ta = norms[b2], tn = norms[(2 + t) * NTOT + nidx];
  float4 av = reinterpret_cast<const float4*>(ar)[threadIdx.x];
  float4 nv = reinterpret_cast<const float4*>(nr)[threadIdx.x];
  float d0 = av.x/ta - nv.x/tn, d1 = av.y/ta - nv.y/tn;
  float d2 = av.z/ta - nv.z/tn, d3 = av.w/ta - nv.w/tn;
  float s = blockSumAll(d0*d0 + d1*d1 + d2*d2 + d3*d3);
  if (threadIdx.x == 0 && valid[j] > 0.0f){
    float h = fmaxf(dpos[j] - s + 1.1f, 0.0f);
    if (h > 0.0f) atomicAdd(lossAcc, (double)h);
  }
}

__global__ void finK(const double* __restrict__ lossAcc, float* __restrict__ out){
  out[0] = (float)(*lossAcc);   // WEIGHT = 1.0
}

// ---------------- launcher ----------------
extern "C" void kernel_launch(void* const* d_in, const int* in_sizes, int n_in,
                              void* d_out, int out_size, void* d_ws, size_t ws_size,
                              hipStream_t stream){
  const float* sf  = (const float*)d_in[0];   // [8,4096,1024] f32
  const float* att = (const float*)d_in[1];   // [8,4096] f32
  char* w = (char*)d_ws;
  size_t off = 0;
  auto alloc = [&](size_t bytes)->void*{
    off = (off + 255) & ~(size_t)255;
    void* p = w + off; off += bytes; return p;
  };
  short* packbf = (short*)alloc((size_t)8 * NTOT * DIM * 2);   // 64 MB bf16 normalized
  float* norms  = (float*)alloc((size_t)8 * NTOT * 4);
  float* sumn   = (float*)alloc((size_t)8 * NTOT * 4);
  float* attm   = (float*)alloc((size_t)NTOT * 4);
  u64*   best1p = (u64*)  alloc((size_t)NTOT * 8);
  int*   best2  = (int*)  alloc((size_t)NTOT * 4);
  int*   ratOk  = (int*)  alloc((size_t)NTOT * 4);
  float* valid  = (float*)alloc((size_t)NTOT * 4);
  float* dpos   = (float*)alloc((size_t)NTOT * 4);
  u64*   nidxp  = (u64*)  alloc((size_t)NNEG * NTOT * 8);
  float* cm1    = (float*)alloc((size_t)32 * NTOT * 4);
  int*   cr1    = (int*)  alloc((size_t)32 * NTOT * 4);
  float* cm2    = (float*)alloc((size_t)32 * NTOT * 4);
  double* lossAcc = (double*)alloc(8);

  initK<<<dim3((NNEG*NTOT + 255)/256), dim3(256), 0, stream>>>(nidxp, best1p, lossAcc);
  rowNormPackK<<<dim3(8*NTOT), dim3(256), 0, stream>>>(sf, norms, sumn, packbf);
  topkMaskK<<<dim3(1), dim3(1024), 0, stream>>>(att + NTOT, attm);
  // pair matrix: best1 (row argmin) + column top-2 chunks
  distMfmaK<false><<<dim3(32,32,1), dim3(256), 0, stream>>>(
      packbf, sumn, nullptr, best1p, cm1, cr1, cm2);
  colMergeK<<<dim3(16), dim3(256), 0, stream>>>(cm1, cr1, cm2, sumn + NTOT, best2, ratOk);
  validDposK<<<dim3(NTOT), dim3(256), 0, stream>>>(sf, norms, best1p, best2, ratOk, attm, valid, dpos);
  // negative mining: anchors = q[best2], fused row argmin per neg frame
  distMfmaK<true><<<dim3(32,32,NNEG), dim3(256), 0, stream>>>(
      packbf, sumn, best2, nidxp, nullptr, nullptr, nullptr);
  dnegHingeK<<<dim3(NTOT, NNEG), dim3(256), 0, stream>>>(sf, norms, best2, nidxp, valid, dpos, lossAcc);
  finK<<<dim3(1), dim3(1), 0, stream>>>(lossAcc, (float*)d_out);
}